// Round 1
// baseline (554.758 us; speedup 1.0000x reference)
//
#include <hip/hip_runtime.h>
#include <math.h>

#define EPS 1e-6f

__device__ __forceinline__ float bcast(float x, int srcLane) {
    return __int_as_float(__builtin_amdgcn_readlane(__float_as_int(x), srcLane));
}

// One wave (64 lanes) per batch pair. Lane i holds row i of recon (B) and orig (A)
// in registers. Cholesky both, then forward-substitute W = L_B^{-1} L_A row by row,
// accumulating ||W||_F^2 = tr(B^{-1} A).
__global__ __launch_bounds__(256, 2) void vae_rec_kernel(const float* __restrict__ recon,
                                                         const float* __restrict__ orig,
                                                         float* __restrict__ out,
                                                         int npairs) {
    const int lane = threadIdx.x & 63;
    const int waveInBlock = threadIdx.x >> 6;
    const int pair = blockIdx.x * 4 + waveInBlock;

    float kl = 0.0f;
    if (pair < npairs) {
        const float* Bm = recon + (size_t)pair * 4096;
        const float* Am = orig + (size_t)pair * 4096;

        float rB[64], rA[64];
        {
            const float4* pb = (const float4*)(Bm + lane * 64);
            const float4* pa = (const float4*)(Am + lane * 64);
#pragma unroll
            for (int i = 0; i < 16; ++i) {
                float4 v = pb[i];
                rB[4 * i + 0] = v.x; rB[4 * i + 1] = v.y;
                rB[4 * i + 2] = v.z; rB[4 * i + 3] = v.w;
            }
#pragma unroll
            for (int i = 0; i < 16; ++i) {
                float4 v = pa[i];
                rA[4 * i + 0] = v.x; rA[4 * i + 1] = v.y;
                rA[4 * i + 2] = v.z; rA[4 * i + 3] = v.w;
            }
        }

        // ---- Cholesky of B (recon) ----
        float pB = 1.0f;
#pragma unroll
        for (int k = 0; k < 64; ++k) {
            float akk = bcast(rB[k], k);
            float d = __builtin_sqrtf(akk);
            pB *= d;
            float inv = 1.0f / d;
            rB[k] *= inv;  // L_B[lane][k] for lane >= k
#pragma unroll
            for (int j = k + 1; j < 64; ++j) {
                float ljk = bcast(rB[k], j);  // L_B[j][k], uniform
                rB[j] = __builtin_fmaf(-rB[k], ljk, rB[j]);
            }
        }

        // ---- Cholesky of A (orig) ----
        float pA = 1.0f;
#pragma unroll
        for (int k = 0; k < 64; ++k) {
            float akk = bcast(rA[k], k);
            float d = __builtin_sqrtf(akk);
            pA *= d;
            float inv = 1.0f / d;
            rA[k] *= inv;
#pragma unroll
            for (int j = k + 1; j < 64; ++j) {
                float ljk = bcast(rA[k], j);
                rA[j] = __builtin_fmaf(-rA[k], ljk, rA[j]);
            }
        }

        // ---- W = L_B^{-1} L_A via forward substitution, fro = ||W||_F^2 ----
        // rA[] is maintained as the residual; row i of W is broadcast from lane i.
        float fro = 0.0f;
#pragma unroll
        for (int i = 0; i < 64; ++i) {
            float bii = bcast(rB[i], i);   // L_B[i][i]
            float inv = 1.0f / bii;
            float t = rB[i] * inv;         // per-lane m: L_B[m][i] / L_B[i][i]
            float acc = 0.0f;
#pragma unroll
            for (int c = 0; c <= i; ++c) {
                float u = bcast(rA[c], i);                 // raw residual of row i -> W[i][c]*bii
                acc = __builtin_fmaf(u, u, acc);           // uniform accumulation of u^2
                rA[c] = __builtin_fmaf(-t, u, rA[c]);      // residual update for lanes m > i
            }
            fro = __builtin_fmaf(acc, inv * inv, fro);
        }

        float logdet = __builtin_logf((pA + EPS) / (pB + EPS));
        kl = 0.5f * (fro - 64.0f + logdet);
    }

    __shared__ float sred[4];
    if (lane == 0) sred[waveInBlock] = kl;
    __syncthreads();
    if (threadIdx.x == 0) {
        float s = sred[0] + sred[1] + sred[2] + sred[3];
        atomicAdd(out + 1, -s);
    }
}

// Encoded: 32x32 Cholesky (for sqrt-det) + trace. Two matrices per wave:
// lanes 0-31 handle matrix 2w, lanes 32-63 handle 2w+1.
__global__ __launch_bounds__(256) void vae_enc_kernel(const float* __restrict__ enc,
                                                      float* __restrict__ out,
                                                      int nmats) {
    const int lane = threadIdx.x & 63;
    const int wv = (int)(blockIdx.x * 4 + (threadIdx.x >> 6));
    const int half = lane & 32;          // 0 or 32
    const int r = lane & 31;             // row within matrix
    const int mat = wv * 2 + (half ? 1 : 0);

    float kl = 0.0f;
    bool valid = (mat < nmats);
    if (valid) {
        const float* M = enc + (size_t)mat * 1024;
        float rm[32];
        {
            const float4* pm = (const float4*)(M + r * 32);
#pragma unroll
            for (int i = 0; i < 8; ++i) {
                float4 v = pm[i];
                rm[4 * i + 0] = v.x; rm[4 * i + 1] = v.y;
                rm[4 * i + 2] = v.z; rm[4 * i + 3] = v.w;
            }
        }

        // trace: capture own diagonal element, reduce within the 32-lane half
        float tr_l = 0.0f;
#pragma unroll
        for (int i = 0; i < 32; ++i)
            if (i == r) tr_l = rm[i];
        float tr = tr_l;
#pragma unroll
        for (int m = 1; m < 32; m <<= 1)
            tr += __shfl_xor(tr, m, 64);  // xor mask < 32 keeps it within the half

        // Cholesky, broadcasts within the half via dynamic-lane shuffle
        float p = 1.0f;
#pragma unroll
        for (int k = 0; k < 32; ++k) {
            float akk = __shfl(rm[k], k + half, 64);
            float d = __builtin_sqrtf(akk);
            p *= d;
            float inv = 1.0f / d;
            rm[k] *= inv;
#pragma unroll
            for (int j = k + 1; j < 32; ++j) {
                float ljk = __shfl(rm[k], j + half, 64);
                rm[j] = __builtin_fmaf(-rm[k], ljk, rm[j]);
            }
        }

        float logdet = __builtin_logf((p + EPS) / (1.0f + EPS));
        kl = 0.5f * (tr - 32.0f + logdet);
    }

    // 8 half-waves per block -> LDS reduce -> 1 atomic
    __shared__ float sred[8];
    if (r == 0) sred[threadIdx.x >> 5] = kl;
    __syncthreads();
    if (threadIdx.x == 0) {
        float s = 0.0f;
#pragma unroll
        for (int i = 0; i < 8; ++i) s += sred[i];
        atomicAdd(out + 2, -s);
    }
}

__global__ void vae_init_kernel(float* __restrict__ out) {
    if (threadIdx.x < 3) out[threadIdx.x] = 0.0f;
}

__global__ void vae_final_kernel(float* __restrict__ out) {
    if (threadIdx.x == 0) out[0] = out[1] + out[2];
}

extern "C" void kernel_launch(void* const* d_in, const int* in_sizes, int n_in,
                              void* d_out, int out_size, void* d_ws, size_t ws_size,
                              hipStream_t stream) {
    const float* recon = (const float*)d_in[0];
    const float* orig = (const float*)d_in[1];
    const float* enc = (const float*)d_in[2];
    float* out = (float*)d_out;

    const int npairs = in_sizes[0] / 4096;   // 8192
    const int nmats = in_sizes[2] / 1024;    // 8192

    vae_init_kernel<<<1, 64, 0, stream>>>(out);

    const int rec_blocks = (npairs + 3) / 4;          // 4 waves/block, 1 pair/wave
    vae_rec_kernel<<<rec_blocks, 256, 0, stream>>>(recon, orig, out, npairs);

    const int enc_blocks = (nmats + 7) / 8;           // 8 matrices/block (2 per wave)
    vae_enc_kernel<<<enc_blocks, 256, 0, stream>>>(enc, out, nmats);

    vae_final_kernel<<<1, 64, 0, stream>>>(out);
}

// Round 2
// 475.981 us; speedup vs baseline: 1.1655x; 1.1655x over previous
//
#include <hip/hip_runtime.h>
#include <math.h>

#define EPS 1e-6f

__device__ __forceinline__ float bcast(float x, int srcLane) {
    return __int_as_float(__builtin_amdgcn_readlane(__float_as_int(x), srcLane));
}

// One wave (64 lanes) per batch pair. Lane i holds row i of recon (B) and orig (A)
// entirely in registers (128 VGPRs of data). launch_bounds min-waves=1 gives the
// allocator a 512-reg budget -> no scratch spills (round-1 lesson: (256,2) spilled,
// 39MB scratch writes, 2.7x VALU inflation).
__global__ __launch_bounds__(256, 1) void vae_rec_kernel(const float* __restrict__ recon,
                                                         const float* __restrict__ orig,
                                                         float* __restrict__ out,
                                                         int npairs) {
    const int lane = threadIdx.x & 63;
    const int waveInBlock = threadIdx.x >> 6;
    const int pair = blockIdx.x * 4 + waveInBlock;

    float kl = 0.0f;
    if (pair < npairs) {
        const float* Bm = recon + (size_t)pair * 4096;
        const float* Am = orig + (size_t)pair * 4096;

        float rB[64], rA[64];
        {
            const float4* pb = (const float4*)(Bm + lane * 64);
            const float4* pa = (const float4*)(Am + lane * 64);
#pragma unroll
            for (int i = 0; i < 16; ++i) {
                float4 vb = pb[i];
                float4 va = pa[i];
                rB[4 * i + 0] = vb.x; rB[4 * i + 1] = vb.y;
                rB[4 * i + 2] = vb.z; rB[4 * i + 3] = vb.w;
                rA[4 * i + 0] = va.x; rA[4 * i + 1] = va.y;
                rA[4 * i + 2] = va.z; rA[4 * i + 3] = va.w;
            }
        }

        // ---- Fused Cholesky of B and A (independent -> 2x ILP per step) ----
        // det accumulated as product of pivots: det = prod a_kk; sdet = sqrt(det).
        float detB = 1.0f, detA = 1.0f;
#pragma unroll
        for (int k = 0; k < 64; ++k) {
            float bkk = bcast(rB[k], k);
            float akk = bcast(rA[k], k);
            detB *= bkk;
            detA *= akk;
            float ib = __builtin_amdgcn_rsqf(bkk);
            float ia = __builtin_amdgcn_rsqf(akk);
            rB[k] *= ib;  // L[lane][k] for lane >= k
            rA[k] *= ia;
#pragma unroll
            for (int j = k + 1; j < 64; ++j) {
                float lbj = bcast(rB[k], j);
                float laj = bcast(rA[k], j);
                rB[j] = __builtin_fmaf(-rB[k], lbj, rB[j]);
                rA[j] = __builtin_fmaf(-rA[k], laj, rA[j]);
            }
        }

        // ---- W = L_B^{-1} L_A via forward substitution, fro = ||W||_F^2 ----
        float fro = 0.0f;
#pragma unroll
        for (int i = 0; i < 64; ++i) {
            float bii = bcast(rB[i], i);            // L_B[i][i]
            float inv = __builtin_amdgcn_rcpf(bii);
            float t = rB[i] * inv;                  // per-lane m: L_B[m][i]/L_B[i][i]
            float acc = 0.0f;
#pragma unroll
            for (int c = 0; c <= i; ++c) {
                float u = bcast(rA[c], i);          // residual row i -> W[i][c]*bii
                acc = __builtin_fmaf(u, u, acc);    // uniform accumulation of u^2
                rA[c] = __builtin_fmaf(-t, u, rA[c]); // residual update (lanes m > i)
            }
            fro = __builtin_fmaf(acc, inv * inv, fro);
        }

        float sdetB = __builtin_sqrtf(detB);
        float sdetA = __builtin_sqrtf(detA);
        float logdet = __builtin_logf((sdetA + EPS) / (sdetB + EPS));
        kl = 0.5f * (fro - 64.0f + logdet);
    }

    __shared__ float sred[4];
    if (lane == 0) sred[waveInBlock] = kl;
    __syncthreads();
    if (threadIdx.x == 0) {
        float s = sred[0] + sred[1] + sred[2] + sred[3];
        atomicAdd(out + 1, -s);
    }
}

// Encoded: 32x32 Cholesky (sqrt-det) + trace. Two matrices per wave (lanes 0-31 /
// 32-63). Broadcasts: two static readlanes + cndmask on the half predicate —
// pure VALU, no ds_bpermute latency (round-1 used dynamic __shfl -> LDS pipe).
__global__ __launch_bounds__(256, 1) void vae_enc_kernel(const float* __restrict__ enc,
                                                         float* __restrict__ out,
                                                         int nmats) {
    const int lane = threadIdx.x & 63;
    const int r = lane & 31;
    const bool hi = lane >= 32;
    const int wv = (int)(blockIdx.x * 4 + (threadIdx.x >> 6));
    const int mat = wv * 2 + (hi ? 1 : 0);

    float kl = 0.0f;
    if (mat < nmats) {
        const float* M = enc + (size_t)mat * 1024;
        float rm[32];
        {
            const float4* pm = (const float4*)(M + r * 32);
#pragma unroll
            for (int i = 0; i < 8; ++i) {
                float4 v = pm[i];
                rm[4 * i + 0] = v.x; rm[4 * i + 1] = v.y;
                rm[4 * i + 2] = v.z; rm[4 * i + 3] = v.w;
            }
        }

        // trace: capture own diagonal element, butterfly-reduce within the half
        float tr = 0.0f;
#pragma unroll
        for (int i = 0; i < 32; ++i)
            if (i == r) tr = rm[i];
#pragma unroll
        for (int m = 1; m < 32; m <<= 1)
            tr += __shfl_xor(tr, m, 64);  // xor mask < 32 stays within the half

        float det = 1.0f;
#pragma unroll
        for (int k = 0; k < 32; ++k) {
            float a0 = bcast(rm[k], k);
            float a1 = bcast(rm[k], k + 32);
            float akk = hi ? a1 : a0;
            det *= akk;
            float inv = __builtin_amdgcn_rsqf(akk);
            rm[k] *= inv;
#pragma unroll
            for (int j = k + 1; j < 32; ++j) {
                float l0 = bcast(rm[k], j);
                float l1 = bcast(rm[k], j + 32);
                float ljk = hi ? l1 : l0;
                rm[j] = __builtin_fmaf(-rm[k], ljk, rm[j]);
            }
        }

        float sdet = __builtin_sqrtf(det);
        float logdet = __builtin_logf((sdet + EPS) / (1.0f + EPS));
        kl = 0.5f * (tr - 32.0f + logdet);
    }

    // 8 half-waves per block -> LDS reduce -> 1 atomic
    __shared__ float sred[8];
    if (r == 0) sred[threadIdx.x >> 5] = kl;
    __syncthreads();
    if (threadIdx.x == 0) {
        float s = 0.0f;
#pragma unroll
        for (int i = 0; i < 8; ++i) s += sred[i];
        atomicAdd(out + 2, -s);
    }
}

__global__ void vae_init_kernel(float* __restrict__ out) {
    if (threadIdx.x < 3) out[threadIdx.x] = 0.0f;
}

__global__ void vae_final_kernel(float* __restrict__ out) {
    if (threadIdx.x == 0) out[0] = out[1] + out[2];
}

extern "C" void kernel_launch(void* const* d_in, const int* in_sizes, int n_in,
                              void* d_out, int out_size, void* d_ws, size_t ws_size,
                              hipStream_t stream) {
    const float* recon = (const float*)d_in[0];
    const float* orig = (const float*)d_in[1];
    const float* enc = (const float*)d_in[2];
    float* out = (float*)d_out;

    const int npairs = in_sizes[0] / 4096;   // 8192
    const int nmats = in_sizes[2] / 1024;    // 8192

    vae_init_kernel<<<1, 64, 0, stream>>>(out);

    const int rec_blocks = (npairs + 3) / 4;          // 4 waves/block, 1 pair/wave
    vae_rec_kernel<<<rec_blocks, 256, 0, stream>>>(recon, orig, out, npairs);

    const int enc_blocks = (nmats + 7) / 8;           // 8 matrices/block (2 per wave)
    vae_enc_kernel<<<enc_blocks, 256, 0, stream>>>(enc, out, nmats);

    vae_final_kernel<<<1, 64, 0, stream>>>(out);
}